// Round 10
// baseline (182.820 us; speedup 1.0000x reference)
//
#include <hip/hip_runtime.h>

#define D_MODEL 1024
#define D_FF    8192
#define N_ELEM  64
#define D1      128
#define BATCH   2048
#define B_T     8      // batch rows per block (main kernel)
#define NJT     8      // j tiles (== XCD count)
#define JT      16     // j per tile

typedef unsigned short u16;
typedef unsigned int   u32;
typedef _Float16 h2    __attribute__((ext_vector_type(2)));
typedef float    f32x4 __attribute__((ext_vector_type(4)));
typedef u32      u32x2 __attribute__((ext_vector_type(2)));
typedef u32      u32x4 __attribute__((ext_vector_type(4)));

__device__ __forceinline__ h2 as_h2(u32 u) { union { u32 i; h2 h; } c; c.i = u; return c.h; }
__device__ __forceinline__ u32 pkh(float a, float b) {
    union { h2 h; u32 u; } c; c.h.x = (_Float16)a; c.h.y = (_Float16)b; return c.u;
}
__device__ __forceinline__ u16 f2h(float f) {
    union { _Float16 h; u16 u; } c; c.h = (_Float16)f; return c.u;
}
__device__ __forceinline__ f32x4 ntload4(const float* p) {
    return __builtin_nontemporal_load((const f32x4*)p);
}
// 2-way f16 dot with f32 accumulate: v_dot2_f32_f16 (2 MAC/inst).
// Validated numerically in rounds 1-9 (absmax 0.03125, passed).
__device__ __forceinline__ float dot2(u32 a, u32 b, float c) {
#if __has_builtin(__builtin_amdgcn_fdot2)
    return __builtin_amdgcn_fdot2(as_h2(a), as_h2(b), c, false);
#else
    const h2 ha = as_h2(a), hb = as_h2(b);
    c = fmaf((float)ha.x, (float)hb.x, c);
    return fmaf((float)ha.y, (float)hb.y, c);
#endif
}
__device__ __forceinline__ float dot8(uint4 w, uint4 q, float c) {
    c = dot2(w.x, q.x, c);
    c = dot2(w.y, q.y, c);
    c = dot2(w.z, q.z, c);
    c = dot2(w.w, q.w, c);
    return c;
}

// ---------------------------------------------------------------------------
// Wave-64 sum reduction on the VALU pipe via DPP. PROVEN WIN in round 9:
// main 63.2 -> 57.2us, VALUBusy 40 -> 44.6% (replaces ~2000cy/wave of serial
// ds_bpermute chains with ~8cy/level VALU DPP adds). Total -> lane 63.
// ---------------------------------------------------------------------------
#if __has_builtin(__builtin_amdgcn_update_dpp)
#define WRITER_LANE 63
#define DPP_ADD(x, ctrl)                                                      \
    x += __builtin_bit_cast(float, __builtin_amdgcn_update_dpp(               \
        0, __builtin_bit_cast(int, x), ctrl, 0xf, 0xf, true))
__device__ __forceinline__ float wave_sum64(float x) {
    DPP_ADD(x, 0x111);   // row_shr:1
    DPP_ADD(x, 0x112);   // row_shr:2
    DPP_ADD(x, 0x114);   // row_shr:4
    DPP_ADD(x, 0x118);   // row_shr:8  -> lane 15+16k holds row-k sum
    DPP_ADD(x, 0x142);   // row_bcast:15 -> lane31 = r0+r1, lane63 = r2+r3
    DPP_ADD(x, 0x143);   // row_bcast:31 -> lane63 = total
    return x;
}
#else
#define WRITER_LANE 0
__device__ __forceinline__ float wave_sum64(float x) {
#pragma unroll
    for (int off = 32; off; off >>= 1) x += __shfl_down(x, off);
    return x;
}
#endif

// ---------------------------------------------------------------------------
// Fused prep: blocks [0,2048) transpose+cast w1 -> w1h [j*64+e][d] f16;
// blocks [2048,6144) cast w2 -> f16. (Verified rounds 1-9.)
// ---------------------------------------------------------------------------
#define TW1_BLOCKS ((D_FF / 64) * (D_MODEL / 64))   // 2048
__global__ __launch_bounds__(256) void prep_weights(const float* __restrict__ w1,
                                                    u16* __restrict__ w1h,
                                                    const float* __restrict__ w2,
                                                    u16* __restrict__ w2h) {
    __shared__ float tile[64][65];
    if (blockIdx.x < TW1_BLOCKS) {
        const int c0 = (blockIdx.x & (D_FF / 64 - 1)) * 64;
        const int d0 = (blockIdx.x >> 7) * 64;          // D_FF/64 == 128
        const int tx = threadIdx.x & 15;
        const int ty = threadIdx.x >> 4;
#pragma unroll
        for (int r = 0; r < 4; ++r) {
            const int row = ty * 4 + r;
            const float4 v = *(const float4*)(w1 + (size_t)(d0 + row) * D_FF + c0 + tx * 4);
            tile[row][tx * 4 + 0] = v.x;
            tile[row][tx * 4 + 1] = v.y;
            tile[row][tx * 4 + 2] = v.z;
            tile[row][tx * 4 + 3] = v.w;
        }
        __syncthreads();
#pragma unroll
        for (int r = 0; r < 4; ++r) {
            const int c = ty * 4 + r;
            ushort4 o;
            o.x = f2h(tile[tx * 4 + 0][c]);
            o.y = f2h(tile[tx * 4 + 1][c]);
            o.z = f2h(tile[tx * 4 + 2][c]);
            o.w = f2h(tile[tx * 4 + 3][c]);
            *(ushort4*)(w1h + (size_t)(c0 + c) * D_MODEL + d0 + tx * 4) = o;
        }
    } else {
        const size_t i = ((size_t)(blockIdx.x - TW1_BLOCKS) * 256 + threadIdx.x) * 8;
        const float4 a = *(const float4*)(w2 + i);
        const float4 b = *(const float4*)(w2 + i + 4);
        ushort4 oa, ob;
        oa.x = f2h(a.x); oa.y = f2h(a.y); oa.z = f2h(a.z); oa.w = f2h(a.w);
        ob.x = f2h(b.x); ob.y = f2h(b.y); ob.z = f2h(b.z); ob.w = f2h(b.w);
        *(ushort4*)(w2h + i)     = oa;
        *(ushort4*)(w2h + i + 4) = ob;
    }
}

// ---------------------------------------------------------------------------
// Main: round-10 = round-9 MINUS the cached-x change (nt hint restored on x
// staging). r9 decomposition: DPP reduce was the win (63.2->57.2us, VALUBusy
// 40->44.6%); cached-x was the FETCH regression (61->81MB: plain x lines
// evict the per-XCD weight working set, w1h 2MB + w2h 2MB ~= L2 capacity,
// forcing HBM weight re-fetches on the critical gather path). nt on x
// protects weight L2-residency; nt on part stores is genuinely streaming.
//   phase 1: 4 j per step, dot2 dots, DPP wave reduce.
//   phase 2: branchless, wave-pair split, 8 dims/thread.
// ---------------------------------------------------------------------------
__global__ __launch_bounds__(256) void sparse_ff_jt(const int* __restrict__ mask,
                                                    const float* __restrict__ x,
                                                    const u16* __restrict__ w1h_,
                                                    const u16* __restrict__ w2h_,
                                                    u16* __restrict__ part) {
    const _Float16* w1h = (const _Float16*)w1h_;
    const _Float16* w2h = (const _Float16*)w2h_;
    __shared__ u16   x_lds[B_T][D_MODEL];   // f16, 16 KB
    __shared__ float r_lds[B_T][JT];
    __shared__ int   m_lds[B_T][JT];

    const int jt = blockIdx.x & (NJT - 1);          // XCD-affine j tile
    const int b0 = (blockIdx.x >> 3) * B_T;
    const int t = threadIdx.x;
    const int wave = t >> 6;
    const int lane = t & 63;

    // stage x rows (f32 NT coalesced -> f16 LDS) + mask row, one barrier
#pragma unroll
    for (int r = 0; r < B_T; ++r) {
        const f32x4 v = ntload4(x + (size_t)(b0 + r) * D_MODEL + t * 4);
        u32x2 o; o.x = pkh(v.x, v.y); o.y = pkh(v.z, v.w);
        *(u32x2*)&x_lds[r][t * 4] = o;
    }
    if (t < B_T * JT) {
        m_lds[t >> 4][t & 15] = mask[(b0 + (t >> 4)) * D1 + jt * JT + (t & 15)];
    }
    __syncthreads();

    // ---- phase 1: wave handles 2 batch rows x 16 j, 4 j per step ----
#pragma unroll
    for (int rep = 0; rep < 2; ++rep) {
        const int bi = wave * 2 + rep;
        // loop-invariant x fragments from LDS (16B each, conflict-free)
        const uint4 xA = *(const uint4*)&x_lds[bi][lane * 8];        // elems lane*8..+8
        const uint4 xB = *(const uint4*)&x_lds[bi][512 + lane * 8];  // elems 512+..

#pragma unroll
        for (int jj = 0; jj < JT; jj += 4) {
            const int j0 = jt * JT + jj;
            const _Float16* c0 = w1h + (size_t)(((j0 + 0) << 6) + m_lds[bi][jj + 0]) * D_MODEL + lane * 8;
            const _Float16* c1 = w1h + (size_t)(((j0 + 1) << 6) + m_lds[bi][jj + 1]) * D_MODEL + lane * 8;
            const _Float16* c2 = w1h + (size_t)(((j0 + 2) << 6) + m_lds[bi][jj + 2]) * D_MODEL + lane * 8;
            const _Float16* c3 = w1h + (size_t)(((j0 + 3) << 6) + m_lds[bi][jj + 3]) * D_MODEL + lane * 8;
            const uint4 a0 = *(const uint4*)c0;
            const uint4 a1 = *(const uint4*)c1;
            const uint4 a2 = *(const uint4*)c2;
            const uint4 a3 = *(const uint4*)c3;
            const uint4 e0 = *(const uint4*)(c0 + 512);
            const uint4 e1 = *(const uint4*)(c1 + 512);
            const uint4 e2 = *(const uint4*)(c2 + 512);
            const uint4 e3 = *(const uint4*)(c3 + 512);

            float s0 = dot8(a0, xA, 0.f); s0 = dot8(e0, xB, s0);
            float s1 = dot8(a1, xA, 0.f); s1 = dot8(e1, xB, s1);
            float s2 = dot8(a2, xA, 0.f); s2 = dot8(e2, xB, s2);
            float s3 = dot8(a3, xA, 0.f); s3 = dot8(e3, xB, s3);

            s0 = wave_sum64(s0);
            s1 = wave_sum64(s1);
            s2 = wave_sum64(s2);
            s3 = wave_sum64(s3);
            if (lane == WRITER_LANE) {
                r_lds[bi][jj + 0] = fmaxf(s0, 0.f);
                r_lds[bi][jj + 1] = fmaxf(s1, 0.f);
                r_lds[bi][jj + 2] = fmaxf(s2, 0.f);
                r_lds[bi][jj + 3] = fmaxf(s3, 0.f);
            }
        }
    }
    __syncthreads();

    // ---- phase 2: branchless, wave-pair split, 8 dims/thread ----
    const int halfsel = t >> 7;            // waves 0-1 -> bi even, 2-3 -> bi odd
    const int d0q = (t & 127) * 8;
#pragma unroll
    for (int p = 0; p < 4; ++p) {
        const int bi = p * 2 + halfsel;
        float a0 = 0.f, a1 = 0.f, a2 = 0.f, a3 = 0.f;
        float a4 = 0.f, a5 = 0.f, a6 = 0.f, a7 = 0.f;
#pragma unroll
        for (int jj = 0; jj < JT; ++jj) {
            const float r = r_lds[bi][jj];          // wave-uniform broadcast
            const _Float16* row = w2h
                + (size_t)(m_lds[bi][jj] * D1 + jt * JT + jj) * D_MODEL + d0q;
            const uint4 v = *(const uint4*)row;
            const h2 q0 = as_h2(v.x), q1 = as_h2(v.y);
            const h2 q2 = as_h2(v.z), q3 = as_h2(v.w);
            a0 = fmaf(r, (float)q0.x, a0); a1 = fmaf(r, (float)q0.y, a1);
            a2 = fmaf(r, (float)q1.x, a2); a3 = fmaf(r, (float)q1.y, a3);
            a4 = fmaf(r, (float)q2.x, a4); a5 = fmaf(r, (float)q2.y, a5);
            a6 = fmaf(r, (float)q3.x, a6); a7 = fmaf(r, (float)q3.y, a7);
        }
        u32x4 o;
        o.x = pkh(a0, a1); o.y = pkh(a2, a3);
        o.z = pkh(a4, a5); o.w = pkh(a6, a7);
        u16* pp = part + ((size_t)jt * BATCH + (b0 + bi)) * D_MODEL + d0q;
        __builtin_nontemporal_store(o, (u32x4*)pp);
    }
}

// ---------------------------------------------------------------------------
// Reduce: res[b] = b2 + sum_jt part[jt][b] (f16 partials); mask echo chunk 0
// ---------------------------------------------------------------------------
__global__ __launch_bounds__(256) void reduce_partials(const int* __restrict__ mask,
                                                       const float* __restrict__ b2,
                                                       const u16* __restrict__ part,
                                                       float* __restrict__ out) {
    const int b = blockIdx.x;
    const int t = threadIdx.x;
    if (t < D1) out[(size_t)b * D1 + t] = (float)mask[b * D1 + t];

    const int d0 = t * 4;
    const float4 bv = *(const float4*)(b2 + d0);
    float a0 = bv.x, a1 = bv.y, a2 = bv.z, a3 = bv.w;
#pragma unroll
    for (int jt = 0; jt < NJT; ++jt) {
        const uint2 v = *(const uint2*)(part + ((size_t)jt * BATCH + b) * D_MODEL + d0);
        const h2 p0 = as_h2(v.x), p1 = as_h2(v.y);
        a0 += (float)p0.x; a1 += (float)p0.y;
        a2 += (float)p1.x; a3 += (float)p1.y;
    }
    *(float4*)(out + (size_t)BATCH * D1 + (size_t)b * D_MODEL + d0) =
        make_float4(a0, a1, a2, a3);
}

// ---------------------------------------------------------------------------
// Fallback (tiny ws): fp32 path, raw strided w1 gather
// ---------------------------------------------------------------------------
__global__ __launch_bounds__(256) void sparse_ff_f32_raw(const int* __restrict__ mask,
                                                         const float* __restrict__ x,
                                                         const float* __restrict__ w1,
                                                         const float* __restrict__ w2,
                                                         const float* __restrict__ b2,
                                                         float* __restrict__ out) {
    __shared__ float x_lds[D_MODEL];
    __shared__ float relu_lds[D1];
    __shared__ int   m_lds[D1];
    const int b = blockIdx.x, t = threadIdx.x;
    const int wave = t >> 6, lane = t & 63;
    *(float4*)&x_lds[t * 4] = *(const float4*)(x + (size_t)b * D_MODEL + t * 4);
    if (t < D1) {
        const int mv = mask[b * D1 + t];
        m_lds[t] = mv;
        out[(size_t)b * D1 + t] = (float)mv;
    }
    __syncthreads();
    for (int jj = 0; jj < 32; ++jj) {
        const int j = wave * 32 + jj;
        const int m = m_lds[j];
        float acc = 0.f;
#pragma unroll
        for (int c = 0; c < 16; ++c) {
            const int d = c * 64 + lane;
            acc = fmaf(w1[(size_t)d * D_FF + j * N_ELEM + m], x_lds[d], acc);
        }
#pragma unroll
        for (int off = 32; off; off >>= 1) acc += __shfl_down(acc, off);
        if (lane == 0) relu_lds[j] = fmaxf(acc, 0.f);
    }
    __syncthreads();
    const int dm0 = t * 4;
    const float4 bv = *(const float4*)(b2 + dm0);
    float a0 = bv.x, a1 = bv.y, a2 = bv.z, a3 = bv.w;
    for (int j = 0; j < D1; ++j) {
        const float r = relu_lds[j];
        if (r > 0.f) {
            const float4 wv = *(const float4*)(w2 + (size_t)(m_lds[j] * D1 + j) * D_MODEL + dm0);
            a0 = fmaf(r, wv.x, a0); a1 = fmaf(r, wv.y, a1);
            a2 = fmaf(r, wv.z, a2); a3 = fmaf(r, wv.w, a3);
        }
    }
    *(float4*)(out + (size_t)BATCH * D1 + (size_t)b * D_MODEL + dm0) =
        make_float4(a0, a1, a2, a3);
}

extern "C" void kernel_launch(void* const* d_in, const int* in_sizes, int n_in,
                              void* d_out, int out_size, void* d_ws, size_t ws_size,
                              hipStream_t stream) {
    const int*   mask = (const int*)d_in[0];
    const float* x    = (const float*)d_in[1];
    const float* w1   = (const float*)d_in[2];
    const float* w2   = (const float*)d_in[3];
    const float* b2   = (const float*)d_in[4];
    float* out = (float*)d_out;

    const size_t w1h_bytes  = (size_t)D_FF * D_MODEL * sizeof(u16);          // 16 MiB
    const size_t w2h_bytes  = (size_t)D_FF * D_MODEL * sizeof(u16);          // 16 MiB
    const size_t part_bytes = (size_t)NJT * BATCH * D_MODEL * sizeof(u16);   // 32 MiB

    if (ws_size >= w1h_bytes + w2h_bytes + part_bytes) {
        u16* w1h  = (u16*)d_ws;
        u16* w2h  = (u16*)((char*)d_ws + w1h_bytes);
        u16* part = (u16*)((char*)d_ws + w1h_bytes + w2h_bytes);
        const int cast_blocks = (D_FF * D_MODEL / 8) / 256;                  // 4096
        prep_weights<<<TW1_BLOCKS + cast_blocks, 256, 0, stream>>>(w1, w1h, w2, w2h);
        sparse_ff_jt<<<(BATCH / B_T) * NJT, 256, 0, stream>>>(mask, x, w1h, w2h, part);
        reduce_partials<<<BATCH, 256, 0, stream>>>(mask, b2, part, out);
    } else {
        sparse_ff_f32_raw<<<BATCH, 256, 0, stream>>>(mask, x, w1, w2, b2, out);
    }
}

// Round 11
// 176.601 us; speedup vs baseline: 1.0352x; 1.0352x over previous
//
#include <hip/hip_runtime.h>

#define D_MODEL 1024
#define D_FF    8192
#define N_ELEM  64
#define D1      128
#define BATCH   2048
#define B_T     8      // batch rows per block (main kernel)
#define NJT     8      // j tiles (== XCD count)
#define JT      16     // j per tile

typedef unsigned short u16;
typedef unsigned int   u32;
typedef _Float16 h2    __attribute__((ext_vector_type(2)));
typedef float    f32x4 __attribute__((ext_vector_type(4)));
typedef u32      u32x2 __attribute__((ext_vector_type(2)));
typedef u32      u32x4 __attribute__((ext_vector_type(4)));

__device__ __forceinline__ h2 as_h2(u32 u) { union { u32 i; h2 h; } c; c.i = u; return c.h; }
__device__ __forceinline__ u32 pkh(float a, float b) {
    union { h2 h; u32 u; } c; c.h.x = (_Float16)a; c.h.y = (_Float16)b; return c.u;
}
__device__ __forceinline__ u16 f2h(float f) {
    union { _Float16 h; u16 u; } c; c.h = (_Float16)f; return c.u;
}
// 2-way f16 dot with f32 accumulate: v_dot2_f32_f16 (2 MAC/inst).
// Validated numerically in rounds 1-10 (absmax 0.03125, passed).
__device__ __forceinline__ float dot2(u32 a, u32 b, float c) {
#if __has_builtin(__builtin_amdgcn_fdot2)
    return __builtin_amdgcn_fdot2(as_h2(a), as_h2(b), c, false);
#else
    const h2 ha = as_h2(a), hb = as_h2(b);
    c = fmaf((float)ha.x, (float)hb.x, c);
    return fmaf((float)ha.y, (float)hb.y, c);
#endif
}
__device__ __forceinline__ float dot8(uint4 w, uint4 q, float c) {
    c = dot2(w.x, q.x, c);
    c = dot2(w.y, q.y, c);
    c = dot2(w.z, q.z, c);
    c = dot2(w.w, q.w, c);
    return c;
}

// ---------------------------------------------------------------------------
// Wave-64 sum reduction on the VALU pipe via DPP. Neutral vs __shfl_down in
// isolation (r8 63.2 vs r10 63.6), part of the verified-best r9 config.
// Total lands in lane 63.
// ---------------------------------------------------------------------------
#if __has_builtin(__builtin_amdgcn_update_dpp)
#define WRITER_LANE 63
#define DPP_ADD(x, ctrl)                                                      \
    x += __builtin_bit_cast(float, __builtin_amdgcn_update_dpp(               \
        0, __builtin_bit_cast(int, x), ctrl, 0xf, 0xf, true))
__device__ __forceinline__ float wave_sum64(float x) {
    DPP_ADD(x, 0x111);   // row_shr:1
    DPP_ADD(x, 0x112);   // row_shr:2
    DPP_ADD(x, 0x114);   // row_shr:4
    DPP_ADD(x, 0x118);   // row_shr:8  -> lane 15+16k holds row-k sum
    DPP_ADD(x, 0x142);   // row_bcast:15 -> lane31 = r0+r1, lane63 = r2+r3
    DPP_ADD(x, 0x143);   // row_bcast:31 -> lane63 = total
    return x;
}
#else
#define WRITER_LANE 0
__device__ __forceinline__ float wave_sum64(float x) {
#pragma unroll
    for (int off = 32; off; off >>= 1) x += __shfl_down(x, off);
    return x;
}
#endif

// ---------------------------------------------------------------------------
// Fused prep: blocks [0,2048) transpose+cast w1 -> w1h [j*64+e][d] f16;
// blocks [2048,6144) cast w2 -> f16. (Verified rounds 1-10.)
// ---------------------------------------------------------------------------
#define TW1_BLOCKS ((D_FF / 64) * (D_MODEL / 64))   // 2048
__global__ __launch_bounds__(256) void prep_weights(const float* __restrict__ w1,
                                                    u16* __restrict__ w1h,
                                                    const float* __restrict__ w2,
                                                    u16* __restrict__ w2h) {
    __shared__ float tile[64][65];
    if (blockIdx.x < TW1_BLOCKS) {
        const int c0 = (blockIdx.x & (D_FF / 64 - 1)) * 64;
        const int d0 = (blockIdx.x >> 7) * 64;          // D_FF/64 == 128
        const int tx = threadIdx.x & 15;
        const int ty = threadIdx.x >> 4;
#pragma unroll
        for (int r = 0; r < 4; ++r) {
            const int row = ty * 4 + r;
            const float4 v = *(const float4*)(w1 + (size_t)(d0 + row) * D_FF + c0 + tx * 4);
            tile[row][tx * 4 + 0] = v.x;
            tile[row][tx * 4 + 1] = v.y;
            tile[row][tx * 4 + 2] = v.z;
            tile[row][tx * 4 + 3] = v.w;
        }
        __syncthreads();
#pragma unroll
        for (int r = 0; r < 4; ++r) {
            const int c = ty * 4 + r;
            ushort4 o;
            o.x = f2h(tile[tx * 4 + 0][c]);
            o.y = f2h(tile[tx * 4 + 1][c]);
            o.z = f2h(tile[tx * 4 + 2][c]);
            o.w = f2h(tile[tx * 4 + 3][c]);
            *(ushort4*)(w1h + (size_t)(c0 + c) * D_MODEL + d0 + tx * 4) = o;
        }
    } else {
        const size_t i = ((size_t)(blockIdx.x - TW1_BLOCKS) * 256 + threadIdx.x) * 8;
        const float4 a = *(const float4*)(w2 + i);
        const float4 b = *(const float4*)(w2 + i + 4);
        ushort4 oa, ob;
        oa.x = f2h(a.x); oa.y = f2h(a.y); oa.z = f2h(a.z); oa.w = f2h(a.w);
        ob.x = f2h(b.x); ob.y = f2h(b.y); ob.z = f2h(b.z); ob.w = f2h(b.w);
        *(ushort4*)(w2h + i)     = oa;
        *(ushort4*)(w2h + i + 4) = ob;
    }
}

// ---------------------------------------------------------------------------
// Main: EXACT round-9 kernel (verified session best: 175.7us total, main
// 57.2-58.2us). The r8/r9/r10 A/B matrix isolated CACHED x staging as the
// active ingredient (+6us): the x load is the first instruction of every
// block; the nt hint skipped cache allocation so block startups stalled on
// ~900cy HBM round trips the 8-block/CU queue can't hide. Plain loads leave
// x L3-resident (8MB << 256MB) after the first jt group -> 7/8 of startups
// hit ~200cy L3/L2. The +20MB FETCH (81 vs 61MB) is time-irrelevant at 25%
// HBM utilization. DPP reduce: neutral in isolation, kept as part of the
// verified config. Do not restructure (eight failed variants bracket this).
//   phase 1: 4 j per step, dot2 dots, DPP wave reduce.
//   phase 2: branchless, wave-pair split, 8 dims/thread.
// ---------------------------------------------------------------------------
__global__ __launch_bounds__(256) void sparse_ff_jt(const int* __restrict__ mask,
                                                    const float* __restrict__ x,
                                                    const u16* __restrict__ w1h_,
                                                    const u16* __restrict__ w2h_,
                                                    u16* __restrict__ part) {
    const _Float16* w1h = (const _Float16*)w1h_;
    const _Float16* w2h = (const _Float16*)w2h_;
    __shared__ u16   x_lds[B_T][D_MODEL];   // f16, 16 KB
    __shared__ float r_lds[B_T][JT];
    __shared__ int   m_lds[B_T][JT];

    const int jt = blockIdx.x & (NJT - 1);          // XCD-affine j tile
    const int b0 = (blockIdx.x >> 3) * B_T;
    const int t = threadIdx.x;
    const int wave = t >> 6;
    const int lane = t & 63;

    // stage x rows (f32 CACHED coalesced -> f16 LDS) + mask row, one barrier
#pragma unroll
    for (int r = 0; r < B_T; ++r) {
        const f32x4 v = *(const f32x4*)(x + (size_t)(b0 + r) * D_MODEL + t * 4);
        u32x2 o; o.x = pkh(v.x, v.y); o.y = pkh(v.z, v.w);
        *(u32x2*)&x_lds[r][t * 4] = o;
    }
    if (t < B_T * JT) {
        m_lds[t >> 4][t & 15] = mask[(b0 + (t >> 4)) * D1 + jt * JT + (t & 15)];
    }
    __syncthreads();

    // ---- phase 1: wave handles 2 batch rows x 16 j, 4 j per step ----
#pragma unroll
    for (int rep = 0; rep < 2; ++rep) {
        const int bi = wave * 2 + rep;
        // loop-invariant x fragments from LDS (16B each, conflict-free)
        const uint4 xA = *(const uint4*)&x_lds[bi][lane * 8];        // elems lane*8..+8
        const uint4 xB = *(const uint4*)&x_lds[bi][512 + lane * 8];  // elems 512+..

#pragma unroll
        for (int jj = 0; jj < JT; jj += 4) {
            const int j0 = jt * JT + jj;
            const _Float16* c0 = w1h + (size_t)(((j0 + 0) << 6) + m_lds[bi][jj + 0]) * D_MODEL + lane * 8;
            const _Float16* c1 = w1h + (size_t)(((j0 + 1) << 6) + m_lds[bi][jj + 1]) * D_MODEL + lane * 8;
            const _Float16* c2 = w1h + (size_t)(((j0 + 2) << 6) + m_lds[bi][jj + 2]) * D_MODEL + lane * 8;
            const _Float16* c3 = w1h + (size_t)(((j0 + 3) << 6) + m_lds[bi][jj + 3]) * D_MODEL + lane * 8;
            const uint4 a0 = *(const uint4*)c0;
            const uint4 a1 = *(const uint4*)c1;
            const uint4 a2 = *(const uint4*)c2;
            const uint4 a3 = *(const uint4*)c3;
            const uint4 e0 = *(const uint4*)(c0 + 512);
            const uint4 e1 = *(const uint4*)(c1 + 512);
            const uint4 e2 = *(const uint4*)(c2 + 512);
            const uint4 e3 = *(const uint4*)(c3 + 512);

            float s0 = dot8(a0, xA, 0.f); s0 = dot8(e0, xB, s0);
            float s1 = dot8(a1, xA, 0.f); s1 = dot8(e1, xB, s1);
            float s2 = dot8(a2, xA, 0.f); s2 = dot8(e2, xB, s2);
            float s3 = dot8(a3, xA, 0.f); s3 = dot8(e3, xB, s3);

            s0 = wave_sum64(s0);
            s1 = wave_sum64(s1);
            s2 = wave_sum64(s2);
            s3 = wave_sum64(s3);
            if (lane == WRITER_LANE) {
                r_lds[bi][jj + 0] = fmaxf(s0, 0.f);
                r_lds[bi][jj + 1] = fmaxf(s1, 0.f);
                r_lds[bi][jj + 2] = fmaxf(s2, 0.f);
                r_lds[bi][jj + 3] = fmaxf(s3, 0.f);
            }
        }
    }
    __syncthreads();

    // ---- phase 2: branchless, wave-pair split, 8 dims/thread ----
    const int halfsel = t >> 7;            // waves 0-1 -> bi even, 2-3 -> bi odd
    const int d0q = (t & 127) * 8;
#pragma unroll
    for (int p = 0; p < 4; ++p) {
        const int bi = p * 2 + halfsel;
        float a0 = 0.f, a1 = 0.f, a2 = 0.f, a3 = 0.f;
        float a4 = 0.f, a5 = 0.f, a6 = 0.f, a7 = 0.f;
#pragma unroll
        for (int jj = 0; jj < JT; ++jj) {
            const float r = r_lds[bi][jj];          // wave-uniform broadcast
            const _Float16* row = w2h
                + (size_t)(m_lds[bi][jj] * D1 + jt * JT + jj) * D_MODEL + d0q;
            const uint4 v = *(const uint4*)row;
            const h2 q0 = as_h2(v.x), q1 = as_h2(v.y);
            const h2 q2 = as_h2(v.z), q3 = as_h2(v.w);
            a0 = fmaf(r, (float)q0.x, a0); a1 = fmaf(r, (float)q0.y, a1);
            a2 = fmaf(r, (float)q1.x, a2); a3 = fmaf(r, (float)q1.y, a3);
            a4 = fmaf(r, (float)q2.x, a4); a5 = fmaf(r, (float)q2.y, a5);
            a6 = fmaf(r, (float)q3.x, a6); a7 = fmaf(r, (float)q3.y, a7);
        }
        u32x4 o;
        o.x = pkh(a0, a1); o.y = pkh(a2, a3);
        o.z = pkh(a4, a5); o.w = pkh(a6, a7);
        u16* pp = part + ((size_t)jt * BATCH + (b0 + bi)) * D_MODEL + d0q;
        __builtin_nontemporal_store(o, (u32x4*)pp);
    }
}

// ---------------------------------------------------------------------------
// Reduce: res[b] = b2 + sum_jt part[jt][b] (f16 partials); mask echo chunk 0
// ---------------------------------------------------------------------------
__global__ __launch_bounds__(256) void reduce_partials(const int* __restrict__ mask,
                                                       const float* __restrict__ b2,
                                                       const u16* __restrict__ part,
                                                       float* __restrict__ out) {
    const int b = blockIdx.x;
    const int t = threadIdx.x;
    if (t < D1) out[(size_t)b * D1 + t] = (float)mask[b * D1 + t];

    const int d0 = t * 4;
    const float4 bv = *(const float4*)(b2 + d0);
    float a0 = bv.x, a1 = bv.y, a2 = bv.z, a3 = bv.w;
#pragma unroll
    for (int jt = 0; jt < NJT; ++jt) {
        const uint2 v = *(const uint2*)(part + ((size_t)jt * BATCH + b) * D_MODEL + d0);
        const h2 p0 = as_h2(v.x), p1 = as_h2(v.y);
        a0 += (float)p0.x; a1 += (float)p0.y;
        a2 += (float)p1.x; a3 += (float)p1.y;
    }
    *(float4*)(out + (size_t)BATCH * D1 + (size_t)b * D_MODEL + d0) =
        make_float4(a0, a1, a2, a3);
}

// ---------------------------------------------------------------------------
// Fallback (tiny ws): fp32 path, raw strided w1 gather
// ---------------------------------------------------------------------------
__global__ __launch_bounds__(256) void sparse_ff_f32_raw(const int* __restrict__ mask,
                                                         const float* __restrict__ x,
                                                         const float* __restrict__ w1,
                                                         const float* __restrict__ w2,
                                                         const float* __restrict__ b2,
                                                         float* __restrict__ out) {
    __shared__ float x_lds[D_MODEL];
    __shared__ float relu_lds[D1];
    __shared__ int   m_lds[D1];
    const int b = blockIdx.x, t = threadIdx.x;
    const int wave = t >> 6, lane = t & 63;
    *(float4*)&x_lds[t * 4] = *(const float4*)(x + (size_t)b * D_MODEL + t * 4);
    if (t < D1) {
        const int mv = mask[b * D1 + t];
        m_lds[t] = mv;
        out[(size_t)b * D1 + t] = (float)mv;
    }
    __syncthreads();
    for (int jj = 0; jj < 32; ++jj) {
        const int j = wave * 32 + jj;
        const int m = m_lds[j];
        float acc = 0.f;
#pragma unroll
        for (int c = 0; c < 16; ++c) {
            const int d = c * 64 + lane;
            acc = fmaf(w1[(size_t)d * D_FF + j * N_ELEM + m], x_lds[d], acc);
        }
#pragma unroll
        for (int off = 32; off; off >>= 1) acc += __shfl_down(acc, off);
        if (lane == 0) relu_lds[j] = fmaxf(acc, 0.f);
    }
    __syncthreads();
    const int dm0 = t * 4;
    const float4 bv = *(const float4*)(b2 + dm0);
    float a0 = bv.x, a1 = bv.y, a2 = bv.z, a3 = bv.w;
    for (int j = 0; j < D1; ++j) {
        const float r = relu_lds[j];
        if (r > 0.f) {
            const float4 wv = *(const float4*)(w2 + (size_t)(m_lds[j] * D1 + j) * D_MODEL + dm0);
            a0 = fmaf(r, wv.x, a0); a1 = fmaf(r, wv.y, a1);
            a2 = fmaf(r, wv.z, a2); a3 = fmaf(r, wv.w, a3);
        }
    }
    *(float4*)(out + (size_t)BATCH * D1 + (size_t)b * D_MODEL + dm0) =
        make_float4(a0, a1, a2, a3);
}

extern "C" void kernel_launch(void* const* d_in, const int* in_sizes, int n_in,
                              void* d_out, int out_size, void* d_ws, size_t ws_size,
                              hipStream_t stream) {
    const int*   mask = (const int*)d_in[0];
    const float* x    = (const float*)d_in[1];
    const float* w1   = (const float*)d_in[2];
    const float* w2   = (const float*)d_in[3];
    const float* b2   = (const float*)d_in[4];
    float* out = (float*)d_out;

    const size_t w1h_bytes  = (size_t)D_FF * D_MODEL * sizeof(u16);          // 16 MiB
    const size_t w2h_bytes  = (size_t)D_FF * D_MODEL * sizeof(u16);          // 16 MiB
    const size_t part_bytes = (size_t)NJT * BATCH * D_MODEL * sizeof(u16);   // 32 MiB

    if (ws_size >= w1h_bytes + w2h_bytes + part_bytes) {
        u16* w1h  = (u16*)d_ws;
        u16* w2h  = (u16*)((char*)d_ws + w1h_bytes);
        u16* part = (u16*)((char*)d_ws + w1h_bytes + w2h_bytes);
        const int cast_blocks = (D_FF * D_MODEL / 8) / 256;                  // 4096
        prep_weights<<<TW1_BLOCKS + cast_blocks, 256, 0, stream>>>(w1, w1h, w2, w2h);
        sparse_ff_jt<<<(BATCH / B_T) * NJT, 256, 0, stream>>>(mask, x, w1h, w2h, part);
        reduce_partials<<<BATCH, 256, 0, stream>>>(mask, b2, part, out);
    } else {
        sparse_ff_f32_raw<<<BATCH, 256, 0, stream>>>(mask, x, w1, w2, b2, out);
    }
}

// Round 12
// 171.750 us; speedup vs baseline: 1.0645x; 1.0282x over previous
//
#include <hip/hip_runtime.h>

#define D_MODEL 1024
#define D_FF    8192
#define N_ELEM  64
#define D1      128
#define BATCH   2048
#define B_T     8      // batch rows per block (main kernel)
#define NJT     8      // j tiles (== XCD count)
#define JT      16     // j per tile

typedef unsigned short u16;
typedef unsigned int   u32;
typedef _Float16 h2    __attribute__((ext_vector_type(2)));
typedef float    f32x4 __attribute__((ext_vector_type(4)));
typedef u32      u32x2 __attribute__((ext_vector_type(2)));
typedef u32      u32x4 __attribute__((ext_vector_type(4)));

__device__ __forceinline__ h2 as_h2(u32 u) { union { u32 i; h2 h; } c; c.i = u; return c.h; }
__device__ __forceinline__ u32 pkh(float a, float b) {
    union { h2 h; u32 u; } c; c.h.x = (_Float16)a; c.h.y = (_Float16)b; return c.u;
}
__device__ __forceinline__ u16 f2h(float f) {
    union { _Float16 h; u16 u; } c; c.h = (_Float16)f; return c.u;
}
// 2-way f16 dot with f32 accumulate: v_dot2_f32_f16 (2 MAC/inst).
// Validated numerically in rounds 1-11 (absmax 0.03125, passed).
__device__ __forceinline__ float dot2(u32 a, u32 b, float c) {
#if __has_builtin(__builtin_amdgcn_fdot2)
    return __builtin_amdgcn_fdot2(as_h2(a), as_h2(b), c, false);
#else
    const h2 ha = as_h2(a), hb = as_h2(b);
    c = fmaf((float)ha.x, (float)hb.x, c);
    return fmaf((float)ha.y, (float)hb.y, c);
#endif
}
__device__ __forceinline__ float dot8(uint4 w, uint4 q, float c) {
    c = dot2(w.x, q.x, c);
    c = dot2(w.y, q.y, c);
    c = dot2(w.z, q.z, c);
    c = dot2(w.w, q.w, c);
    return c;
}

// ---------------------------------------------------------------------------
// Wave-64 sum reduction on the VALU pipe via DPP. Neutral vs __shfl_down in
// isolation (r8 63.2 vs r10 63.6), part of the verified-best r9/r11 config.
// Total lands in lane 63.
// ---------------------------------------------------------------------------
#if __has_builtin(__builtin_amdgcn_update_dpp)
#define WRITER_LANE 63
#define DPP_ADD(x, ctrl)                                                      \
    x += __builtin_bit_cast(float, __builtin_amdgcn_update_dpp(               \
        0, __builtin_bit_cast(int, x), ctrl, 0xf, 0xf, true))
__device__ __forceinline__ float wave_sum64(float x) {
    DPP_ADD(x, 0x111);   // row_shr:1
    DPP_ADD(x, 0x112);   // row_shr:2
    DPP_ADD(x, 0x114);   // row_shr:4
    DPP_ADD(x, 0x118);   // row_shr:8  -> lane 15+16k holds row-k sum
    DPP_ADD(x, 0x142);   // row_bcast:15 -> lane31 = r0+r1, lane63 = r2+r3
    DPP_ADD(x, 0x143);   // row_bcast:31 -> lane63 = total
    return x;
}
#else
#define WRITER_LANE 0
__device__ __forceinline__ float wave_sum64(float x) {
#pragma unroll
    for (int off = 32; off; off >>= 1) x += __shfl_down(x, off);
    return x;
}
#endif

// ---------------------------------------------------------------------------
// Fused prep: blocks [0,2048) transpose+cast w1 -> w1h [j*64+e][d] f16;
// blocks [2048,6144) cast w2 -> f16. (Verified rounds 1-11; BW-bound,
// ~128MB total traffic ~= 20us roofline.)
// ---------------------------------------------------------------------------
#define TW1_BLOCKS ((D_FF / 64) * (D_MODEL / 64))   // 2048
__global__ __launch_bounds__(256) void prep_weights(const float* __restrict__ w1,
                                                    u16* __restrict__ w1h,
                                                    const float* __restrict__ w2,
                                                    u16* __restrict__ w2h) {
    __shared__ float tile[64][65];
    if (blockIdx.x < TW1_BLOCKS) {
        const int c0 = (blockIdx.x & (D_FF / 64 - 1)) * 64;
        const int d0 = (blockIdx.x >> 7) * 64;          // D_FF/64 == 128
        const int tx = threadIdx.x & 15;
        const int ty = threadIdx.x >> 4;
#pragma unroll
        for (int r = 0; r < 4; ++r) {
            const int row = ty * 4 + r;
            const float4 v = *(const float4*)(w1 + (size_t)(d0 + row) * D_FF + c0 + tx * 4);
            tile[row][tx * 4 + 0] = v.x;
            tile[row][tx * 4 + 1] = v.y;
            tile[row][tx * 4 + 2] = v.z;
            tile[row][tx * 4 + 3] = v.w;
        }
        __syncthreads();
#pragma unroll
        for (int r = 0; r < 4; ++r) {
            const int c = ty * 4 + r;
            ushort4 o;
            o.x = f2h(tile[tx * 4 + 0][c]);
            o.y = f2h(tile[tx * 4 + 1][c]);
            o.z = f2h(tile[tx * 4 + 2][c]);
            o.w = f2h(tile[tx * 4 + 3][c]);
            *(ushort4*)(w1h + (size_t)(c0 + c) * D_MODEL + d0 + tx * 4) = o;
        }
    } else {
        const size_t i = ((size_t)(blockIdx.x - TW1_BLOCKS) * 256 + threadIdx.x) * 8;
        const float4 a = *(const float4*)(w2 + i);
        const float4 b = *(const float4*)(w2 + i + 4);
        ushort4 oa, ob;
        oa.x = f2h(a.x); oa.y = f2h(a.y); oa.z = f2h(a.z); oa.w = f2h(a.w);
        ob.x = f2h(b.x); ob.y = f2h(b.y); ob.z = f2h(b.z); ob.w = f2h(b.w);
        *(ushort4*)(w2h + i)     = oa;
        *(ushort4*)(w2h + i + 4) = ob;
    }
}

// ---------------------------------------------------------------------------
// Main: r9/r11 verified-best kernel (main 57.2-58.2us, total 175.7/176.6)
// with ONE change: part stores are now CACHED (nt removed). Theory: nt
// stores bypass L3 -> reduce_partials reads 32MB from HBM at the BW ceiling
// (~7us). Cached stores write back through L3 (256MB >> 32MB) at kernel end
// -> reduce reads become L3 hits. Same time-beats-traffic mechanism as the
// cached-x win (r9/r11 A/B). Revert trigger: main > 59.5us.
//   Cached x staging: the active r9 ingredient (+6us) - x load is the first
//   instruction of every block; L3-resident x turns ~900cy HBM startup
//   stalls into ~200cy L3/L2 hits for 7/8 of blocks.
//   phase 1: 4 j per step, dot2 dots, DPP wave reduce.
//   phase 2: branchless, wave-pair split, 8 dims/thread.
// ---------------------------------------------------------------------------
__global__ __launch_bounds__(256) void sparse_ff_jt(const int* __restrict__ mask,
                                                    const float* __restrict__ x,
                                                    const u16* __restrict__ w1h_,
                                                    const u16* __restrict__ w2h_,
                                                    u16* __restrict__ part) {
    const _Float16* w1h = (const _Float16*)w1h_;
    const _Float16* w2h = (const _Float16*)w2h_;
    __shared__ u16   x_lds[B_T][D_MODEL];   // f16, 16 KB
    __shared__ float r_lds[B_T][JT];
    __shared__ int   m_lds[B_T][JT];

    const int jt = blockIdx.x & (NJT - 1);          // XCD-affine j tile
    const int b0 = (blockIdx.x >> 3) * B_T;
    const int t = threadIdx.x;
    const int wave = t >> 6;
    const int lane = t & 63;

    // stage x rows (f32 CACHED coalesced -> f16 LDS) + mask row, one barrier
#pragma unroll
    for (int r = 0; r < B_T; ++r) {
        const f32x4 v = *(const f32x4*)(x + (size_t)(b0 + r) * D_MODEL + t * 4);
        u32x2 o; o.x = pkh(v.x, v.y); o.y = pkh(v.z, v.w);
        *(u32x2*)&x_lds[r][t * 4] = o;
    }
    if (t < B_T * JT) {
        m_lds[t >> 4][t & 15] = mask[(b0 + (t >> 4)) * D1 + jt * JT + (t & 15)];
    }
    __syncthreads();

    // ---- phase 1: wave handles 2 batch rows x 16 j, 4 j per step ----
#pragma unroll
    for (int rep = 0; rep < 2; ++rep) {
        const int bi = wave * 2 + rep;
        // loop-invariant x fragments from LDS (16B each, conflict-free)
        const uint4 xA = *(const uint4*)&x_lds[bi][lane * 8];        // elems lane*8..+8
        const uint4 xB = *(const uint4*)&x_lds[bi][512 + lane * 8];  // elems 512+..

#pragma unroll
        for (int jj = 0; jj < JT; jj += 4) {
            const int j0 = jt * JT + jj;
            const _Float16* c0 = w1h + (size_t)(((j0 + 0) << 6) + m_lds[bi][jj + 0]) * D_MODEL + lane * 8;
            const _Float16* c1 = w1h + (size_t)(((j0 + 1) << 6) + m_lds[bi][jj + 1]) * D_MODEL + lane * 8;
            const _Float16* c2 = w1h + (size_t)(((j0 + 2) << 6) + m_lds[bi][jj + 2]) * D_MODEL + lane * 8;
            const _Float16* c3 = w1h + (size_t)(((j0 + 3) << 6) + m_lds[bi][jj + 3]) * D_MODEL + lane * 8;
            const uint4 a0 = *(const uint4*)c0;
            const uint4 a1 = *(const uint4*)c1;
            const uint4 a2 = *(const uint4*)c2;
            const uint4 a3 = *(const uint4*)c3;
            const uint4 e0 = *(const uint4*)(c0 + 512);
            const uint4 e1 = *(const uint4*)(c1 + 512);
            const uint4 e2 = *(const uint4*)(c2 + 512);
            const uint4 e3 = *(const uint4*)(c3 + 512);

            float s0 = dot8(a0, xA, 0.f); s0 = dot8(e0, xB, s0);
            float s1 = dot8(a1, xA, 0.f); s1 = dot8(e1, xB, s1);
            float s2 = dot8(a2, xA, 0.f); s2 = dot8(e2, xB, s2);
            float s3 = dot8(a3, xA, 0.f); s3 = dot8(e3, xB, s3);

            s0 = wave_sum64(s0);
            s1 = wave_sum64(s1);
            s2 = wave_sum64(s2);
            s3 = wave_sum64(s3);
            if (lane == WRITER_LANE) {
                r_lds[bi][jj + 0] = fmaxf(s0, 0.f);
                r_lds[bi][jj + 1] = fmaxf(s1, 0.f);
                r_lds[bi][jj + 2] = fmaxf(s2, 0.f);
                r_lds[bi][jj + 3] = fmaxf(s3, 0.f);
            }
        }
    }
    __syncthreads();

    // ---- phase 2: branchless, wave-pair split, 8 dims/thread ----
    const int halfsel = t >> 7;            // waves 0-1 -> bi even, 2-3 -> bi odd
    const int d0q = (t & 127) * 8;
#pragma unroll
    for (int p = 0; p < 4; ++p) {
        const int bi = p * 2 + halfsel;
        float a0 = 0.f, a1 = 0.f, a2 = 0.f, a3 = 0.f;
        float a4 = 0.f, a5 = 0.f, a6 = 0.f, a7 = 0.f;
#pragma unroll
        for (int jj = 0; jj < JT; ++jj) {
            const float r = r_lds[bi][jj];          // wave-uniform broadcast
            const _Float16* row = w2h
                + (size_t)(m_lds[bi][jj] * D1 + jt * JT + jj) * D_MODEL + d0q;
            const uint4 v = *(const uint4*)row;
            const h2 q0 = as_h2(v.x), q1 = as_h2(v.y);
            const h2 q2 = as_h2(v.z), q3 = as_h2(v.w);
            a0 = fmaf(r, (float)q0.x, a0); a1 = fmaf(r, (float)q0.y, a1);
            a2 = fmaf(r, (float)q1.x, a2); a3 = fmaf(r, (float)q1.y, a3);
            a4 = fmaf(r, (float)q2.x, a4); a5 = fmaf(r, (float)q2.y, a5);
            a6 = fmaf(r, (float)q3.x, a6); a7 = fmaf(r, (float)q3.y, a7);
        }
        u32x4 o;
        o.x = pkh(a0, a1); o.y = pkh(a2, a3);
        o.z = pkh(a4, a5); o.w = pkh(a6, a7);
        u16* pp = part + ((size_t)jt * BATCH + (b0 + bi)) * D_MODEL + d0q;
        *(u32x4*)pp = o;                       // CACHED store (was nt): L3-resident for reduce
    }
}

// ---------------------------------------------------------------------------
// Reduce: res[b] = b2 + sum_jt part[jt][b] (f16 partials); mask echo chunk 0.
// With cached part stores, the 32MB of part reads hit L3 instead of HBM.
// ---------------------------------------------------------------------------
__global__ __launch_bounds__(256) void reduce_partials(const int* __restrict__ mask,
                                                       const float* __restrict__ b2,
                                                       const u16* __restrict__ part,
                                                       float* __restrict__ out) {
    const int b = blockIdx.x;
    const int t = threadIdx.x;
    if (t < D1) out[(size_t)b * D1 + t] = (float)mask[b * D1 + t];

    const int d0 = t * 4;
    const float4 bv = *(const float4*)(b2 + d0);
    float a0 = bv.x, a1 = bv.y, a2 = bv.z, a3 = bv.w;
#pragma unroll
    for (int jt = 0; jt < NJT; ++jt) {
        const uint2 v = *(const uint2*)(part + ((size_t)jt * BATCH + b) * D_MODEL + d0);
        const h2 p0 = as_h2(v.x), p1 = as_h2(v.y);
        a0 += (float)p0.x; a1 += (float)p0.y;
        a2 += (float)p1.x; a3 += (float)p1.y;
    }
    *(float4*)(out + (size_t)BATCH * D1 + (size_t)b * D_MODEL + d0) =
        make_float4(a0, a1, a2, a3);
}

// ---------------------------------------------------------------------------
// Fallback (tiny ws): fp32 path, raw strided w1 gather
// ---------------------------------------------------------------------------
__global__ __launch_bounds__(256) void sparse_ff_f32_raw(const int* __restrict__ mask,
                                                         const float* __restrict__ x,
                                                         const float* __restrict__ w1,
                                                         const float* __restrict__ w2,
                                                         const float* __restrict__ b2,
                                                         float* __restrict__ out) {
    __shared__ float x_lds[D_MODEL];
    __shared__ float relu_lds[D1];
    __shared__ int   m_lds[D1];
    const int b = blockIdx.x, t = threadIdx.x;
    const int wave = t >> 6, lane = t & 63;
    *(float4*)&x_lds[t * 4] = *(const float4*)(x + (size_t)b * D_MODEL + t * 4);
    if (t < D1) {
        const int mv = mask[b * D1 + t];
        m_lds[t] = mv;
        out[(size_t)b * D1 + t] = (float)mv;
    }
    __syncthreads();
    for (int jj = 0; jj < 32; ++jj) {
        const int j = wave * 32 + jj;
        const int m = m_lds[j];
        float acc = 0.f;
#pragma unroll
        for (int c = 0; c < 16; ++c) {
            const int d = c * 64 + lane;
            acc = fmaf(w1[(size_t)d * D_FF + j * N_ELEM + m], x_lds[d], acc);
        }
#pragma unroll
        for (int off = 32; off; off >>= 1) acc += __shfl_down(acc, off);
        if (lane == 0) relu_lds[j] = fmaxf(acc, 0.f);
    }
    __syncthreads();
    const int dm0 = t * 4;
    const float4 bv = *(const float4*)(b2 + dm0);
    float a0 = bv.x, a1 = bv.y, a2 = bv.z, a3 = bv.w;
    for (int j = 0; j < D1; ++j) {
        const float r = relu_lds[j];
        if (r > 0.f) {
            const float4 wv = *(const float4*)(w2 + (size_t)(m_lds[j] * D1 + j) * D_MODEL + dm0);
            a0 = fmaf(r, wv.x, a0); a1 = fmaf(r, wv.y, a1);
            a2 = fmaf(r, wv.z, a2); a3 = fmaf(r, wv.w, a3);
        }
    }
    *(float4*)(out + (size_t)BATCH * D1 + (size_t)b * D_MODEL + dm0) =
        make_float4(a0, a1, a2, a3);
}

extern "C" void kernel_launch(void* const* d_in, const int* in_sizes, int n_in,
                              void* d_out, int out_size, void* d_ws, size_t ws_size,
                              hipStream_t stream) {
    const int*   mask = (const int*)d_in[0];
    const float* x    = (const float*)d_in[1];
    const float* w1   = (const float*)d_in[2];
    const float* w2   = (const float*)d_in[3];
    const float* b2   = (const float*)d_in[4];
    float* out = (float*)d_out;

    const size_t w1h_bytes  = (size_t)D_FF * D_MODEL * sizeof(u16);          // 16 MiB
    const size_t w2h_bytes  = (size_t)D_FF * D_MODEL * sizeof(u16);          // 16 MiB
    const size_t part_bytes = (size_t)NJT * BATCH * D_MODEL * sizeof(u16);   // 32 MiB

    if (ws_size >= w1h_bytes + w2h_bytes + part_bytes) {
        u16* w1h  = (u16*)d_ws;
        u16* w2h  = (u16*)((char*)d_ws + w1h_bytes);
        u16* part = (u16*)((char*)d_ws + w1h_bytes + w2h_bytes);
        const int cast_blocks = (D_FF * D_MODEL / 8) / 256;                  // 4096
        prep_weights<<<TW1_BLOCKS + cast_blocks, 256, 0, stream>>>(w1, w1h, w2, w2h);
        sparse_ff_jt<<<(BATCH / B_T) * NJT, 256, 0, stream>>>(mask, x, w1h, w2h, part);
        reduce_partials<<<BATCH, 256, 0, stream>>>(mask, b2, part, out);
    } else {
        sparse_ff_f32_raw<<<BATCH, 256, 0, stream>>>(mask, x, w1, w2, b2, out);
    }
}